// Round 2
// baseline (691.942 us; speedup 1.0000x reference)
//
#include <hip/hip_runtime.h>
#include <math.h>

#define L_DIM 4096
#define B_DIM 32
#define H_DIM 1024

// Kernel 0: transpose hidden (H,B) -> hT (B,H). 128 KB one-time, ~2 us.
__global__ void transpose_hidden_k(const float* __restrict__ hidden,
                                   float* __restrict__ hT) {
    int tid = blockIdx.x * blockDim.x + threadIdx.x; // tid = h*B + b
    int h = tid / B_DIM;
    int b = tid % B_DIM;
    hT[b * H_DIM + h] = hidden[tid];
}

__device__ __forceinline__ float dot4(float4 a, float4 b) {
    return a.x * b.x + a.y * b.y + a.z * b.z + a.w * b.w;
}

// Kernel 1: energies[b][l] = dot(hT[b][:], enc[l][b][:])
//
// Redesign vs previous round (which was ~1.7 TB/s effective if serial-decomp
// theory holds): one b per BLOCK, 64 l-rows per block, 16 rows per wave.
//  - hidden row lives in 16 VGPRs per lane (4 float4), loaded once per wave
//    from L2-resident hT: no LDS, no __syncthreads, no block-stage overhead.
//  - 4 rows processed per iteration -> 16 float4 global loads (16 KB/wave)
//    in flight, 4 independent shuffle-reduce chains overlap via ILP.
//  - 2048 blocks of 256 thr (vs 32768 tiny blocks): 16x more work per block,
//    dispatch overhead amortized. b fastest in blockIdx for HBM spread.
//  - lane 0 packs 4 results into one float4 store.
__global__ __launch_bounds__(256) void energies_k(const float* __restrict__ hT,
                                                  const float* __restrict__ enc,
                                                  float* __restrict__ out) {
    const int bid  = blockIdx.x;
    const int b    = bid & 31;       // b fastest
    const int cg   = bid >> 5;       // chunk 0..63
    const int t    = threadIdx.x;
    const int wave = t >> 6;
    const int lane = t & 63;

    // hidden row b: 1024 floats = 256 float4; each lane keeps 4 of them.
    const float4* hp = (const float4*)(hT + (size_t)b * H_DIM);
    const float4 h0 = hp[lane      ];
    const float4 h1 = hp[lane +  64];
    const float4 h2 = hp[lane + 128];
    const float4 h3 = hp[lane + 192];

    const int l0 = cg * 64 + wave * 16;           // this wave's first row
    const size_t rowstride = (size_t)B_DIM * H_DIM; // floats between l's
    const float* rp = enc + (size_t)l0 * rowstride + (size_t)b * H_DIM;
    float* orow = out + (size_t)b * L_DIM + l0;

    for (int i = 0; i < 16; i += 4) {
        const float4* r0 = (const float4*)(rp + (size_t)(i + 0) * rowstride);
        const float4* r1 = (const float4*)(rp + (size_t)(i + 1) * rowstride);
        const float4* r2 = (const float4*)(rp + (size_t)(i + 2) * rowstride);
        const float4* r3 = (const float4*)(rp + (size_t)(i + 3) * rowstride);

        float4 a00 = r0[lane], a01 = r0[lane + 64], a02 = r0[lane + 128], a03 = r0[lane + 192];
        float4 a10 = r1[lane], a11 = r1[lane + 64], a12 = r1[lane + 128], a13 = r1[lane + 192];
        float4 a20 = r2[lane], a21 = r2[lane + 64], a22 = r2[lane + 128], a23 = r2[lane + 192];
        float4 a30 = r3[lane], a31 = r3[lane + 64], a32 = r3[lane + 128], a33 = r3[lane + 192];

        float acc0 = dot4(a00, h0) + dot4(a01, h1) + dot4(a02, h2) + dot4(a03, h3);
        float acc1 = dot4(a10, h0) + dot4(a11, h1) + dot4(a12, h2) + dot4(a13, h3);
        float acc2 = dot4(a20, h0) + dot4(a21, h1) + dot4(a22, h2) + dot4(a23, h3);
        float acc3 = dot4(a30, h0) + dot4(a31, h1) + dot4(a32, h2) + dot4(a33, h3);

#pragma unroll
        for (int off = 32; off > 0; off >>= 1) {
            acc0 += __shfl_down(acc0, off, 64);
            acc1 += __shfl_down(acc1, off, 64);
            acc2 += __shfl_down(acc2, off, 64);
            acc3 += __shfl_down(acc3, off, 64);
        }
        if (lane == 0) {
            float4 o = make_float4(acc0, acc1, acc2, acc3);
            *(float4*)(orow + i) = o;   // l0 % 16 == 0, i % 4 == 0 -> aligned
        }
    }
}

// Kernel 2: in-place softmax over L for each b. One 1024-thread block per b.
__global__ __launch_bounds__(1024) void softmax_k(float* __restrict__ out) {
    __shared__ float red[16];
    const int b = blockIdx.x;
    float* row = out + (size_t)b * L_DIM;
    const int t = threadIdx.x;
    const int lane = t & 63;
    const int wave = t >> 6;

    float vals[4];
    float m = -INFINITY;
#pragma unroll
    for (int k = 0; k < 4; ++k) {
        vals[k] = row[t + k * 1024];
        m = fmaxf(m, vals[k]);
    }
#pragma unroll
    for (int off = 32; off > 0; off >>= 1)
        m = fmaxf(m, __shfl_down(m, off, 64));
    if (lane == 0) red[wave] = m;
    __syncthreads();
    float mm = red[0];
#pragma unroll
    for (int w = 1; w < 16; ++w) mm = fmaxf(mm, red[w]);
    __syncthreads();

    float s = 0.f;
#pragma unroll
    for (int k = 0; k < 4; ++k) {
        vals[k] = expf(vals[k] - mm);
        s += vals[k];
    }
#pragma unroll
    for (int off = 32; off > 0; off >>= 1)
        s += __shfl_down(s, off, 64);
    if (lane == 0) red[wave] = s;
    __syncthreads();
    float ss = 0.f;
#pragma unroll
    for (int w = 0; w < 16; ++w) ss += red[w];

    const float inv = 1.0f / ss;
#pragma unroll
    for (int k = 0; k < 4; ++k)
        row[t + k * 1024] = vals[k] * inv;
}

extern "C" void kernel_launch(void* const* d_in, const int* in_sizes, int n_in,
                              void* d_out, int out_size, void* d_ws, size_t ws_size,
                              hipStream_t stream) {
    const float* hidden = (const float*)d_in[0];   // (H, B)
    const float* enc    = (const float*)d_in[1];   // (L, B, H)
    float* out = (float*)d_out;                    // (B, 1, L) flat = b*L + l
    float* hT  = (float*)d_ws;                     // (B, H) scratch, 128 KB

    transpose_hidden_k<<<(H_DIM * B_DIM) / 256, 256, 0, stream>>>(hidden, hT);
    energies_k<<<B_DIM * 64, 256, 0, stream>>>(hT, enc, out);
    softmax_k<<<B_DIM, 1024, 0, stream>>>(out);
}

// Round 3
// 670.525 us; speedup vs baseline: 1.0319x; 1.0319x over previous
//
#include <hip/hip_runtime.h>
#include <math.h>

#define L_DIM 4096
#define B_DIM 32
#define H_DIM 1024

__device__ __forceinline__ float dot4(float4 a, float4 b) {
    return a.x * b.x + a.y * b.y + a.z * b.z + a.w * b.w;
}

// Kernel 1: energies[b][l] = dot(hidden[:,b], enc[l][b][:])
//
// NO workspace, NO transpose kernel: hidden's column b (4 KB) is gathered
// once per block from L2 (hidden is 128 KB -> fully L2/L3 resident) into LDS
// with strided scalar loads, then reused by all 16 rows the block computes.
//
// Proven-good memory pattern from round 0 (each wave reads a 4 KB enc row as
// 4x fully-contiguous 1 KB transactions) + ILP: 4 rows in flight per wave
// (16 float4 loads outstanding, 4 independent reduce chains), packed float4
// store of the 4 results. 8192 blocks of 256 thr; b fastest -> 32 consecutive
// blocks read one contiguous 2 MB stripe of enc.
__global__ __launch_bounds__(256) void energies_k(const float* __restrict__ hidden,
                                                  const float* __restrict__ enc,
                                                  float* __restrict__ out) {
    __shared__ float sh[H_DIM];
    const int bid  = blockIdx.x;
    const int b    = bid & 31;       // b fastest
    const int cg   = bid >> 5;       // row-chunk 0..255 (16 rows each)
    const int t    = threadIdx.x;
    const int wave = t >> 6;
    const int lane = t & 63;

    // stage hidden[:, b] into LDS: sh[h] = hidden[h*B + b]
#pragma unroll
    for (int k = 0; k < 4; ++k)
        sh[t + k * 256] = hidden[(t + k * 256) * B_DIM + b];
    __syncthreads();

    const int l0 = cg * 16 + wave * 4;              // this wave's 4 rows
    const size_t rowstride = (size_t)B_DIM * H_DIM; // floats between l's
    const float* rp = enc + (size_t)l0 * rowstride + (size_t)b * H_DIM;
    const float4* sp = (const float4*)sh;

    const float4* r0 = (const float4*)(rp);
    const float4* r1 = (const float4*)(rp + rowstride);
    const float4* r2 = (const float4*)(rp + 2 * rowstride);
    const float4* r3 = (const float4*)(rp + 3 * rowstride);

    float4 a00 = r0[lane], a01 = r0[lane + 64], a02 = r0[lane + 128], a03 = r0[lane + 192];
    float4 a10 = r1[lane], a11 = r1[lane + 64], a12 = r1[lane + 128], a13 = r1[lane + 192];
    float4 a20 = r2[lane], a21 = r2[lane + 64], a22 = r2[lane + 128], a23 = r2[lane + 192];
    float4 a30 = r3[lane], a31 = r3[lane + 64], a32 = r3[lane + 128], a33 = r3[lane + 192];

    float4 h0 = sp[lane], h1 = sp[lane + 64], h2 = sp[lane + 128], h3 = sp[lane + 192];

    float acc0 = dot4(a00, h0) + dot4(a01, h1) + dot4(a02, h2) + dot4(a03, h3);
    float acc1 = dot4(a10, h0) + dot4(a11, h1) + dot4(a12, h2) + dot4(a13, h3);
    float acc2 = dot4(a20, h0) + dot4(a21, h1) + dot4(a22, h2) + dot4(a23, h3);
    float acc3 = dot4(a30, h0) + dot4(a31, h1) + dot4(a32, h2) + dot4(a33, h3);

#pragma unroll
    for (int off = 32; off > 0; off >>= 1) {
        acc0 += __shfl_down(acc0, off, 64);
        acc1 += __shfl_down(acc1, off, 64);
        acc2 += __shfl_down(acc2, off, 64);
        acc3 += __shfl_down(acc3, off, 64);
    }
    if (lane == 0) {
        float4 o = make_float4(acc0, acc1, acc2, acc3);
        *(float4*)(out + (size_t)b * L_DIM + l0) = o;  // l0 % 4 == 0 -> aligned
    }
}

// Kernel 2: in-place softmax over L for each b. One 1024-thread block per b.
__global__ __launch_bounds__(1024) void softmax_k(float* __restrict__ out) {
    __shared__ float red[16];
    const int b = blockIdx.x;
    float* row = out + (size_t)b * L_DIM;
    const int t = threadIdx.x;
    const int lane = t & 63;
    const int wave = t >> 6;

    float vals[4];
    float m = -INFINITY;
#pragma unroll
    for (int k = 0; k < 4; ++k) {
        vals[k] = row[t + k * 1024];
        m = fmaxf(m, vals[k]);
    }
#pragma unroll
    for (int off = 32; off > 0; off >>= 1)
        m = fmaxf(m, __shfl_down(m, off, 64));
    if (lane == 0) red[wave] = m;
    __syncthreads();
    float mm = red[0];
#pragma unroll
    for (int w = 1; w < 16; ++w) mm = fmaxf(mm, red[w]);
    __syncthreads();

    float s = 0.f;
#pragma unroll
    for (int k = 0; k < 4; ++k) {
        vals[k] = expf(vals[k] - mm);
        s += vals[k];
    }
#pragma unroll
    for (int off = 32; off > 0; off >>= 1)
        s += __shfl_down(s, off, 64);
    if (lane == 0) red[wave] = s;
    __syncthreads();
    float ss = 0.f;
#pragma unroll
    for (int w = 0; w < 16; ++w) ss += red[w];

    const float inv = 1.0f / ss;
#pragma unroll
    for (int k = 0; k < 4; ++k)
        row[t + k * 1024] = vals[k] * inv;
}

extern "C" void kernel_launch(void* const* d_in, const int* in_sizes, int n_in,
                              void* d_out, int out_size, void* d_ws, size_t ws_size,
                              hipStream_t stream) {
    const float* hidden = (const float*)d_in[0];   // (H, B)
    const float* enc    = (const float*)d_in[1];   // (L, B, H)
    float* out = (float*)d_out;                    // (B, 1, L) flat = b*L + l
    (void)d_ws; (void)ws_size;                     // workspace deliberately unused

    energies_k<<<B_DIM * 256, 256, 0, stream>>>(hidden, enc, out);
    softmax_k<<<B_DIM, 1024, 0, stream>>>(out);
}